// Round 11
// baseline (220.759 us; speedup 1.0000x reference)
//
#include <hip/hip_runtime.h>
#include <math.h>

#define NN 32768
#define NG 256
#define DEG 8
#define HC 256
#define NCAT 1088          // Q(256)|KV interleaved(512)|S(768..1023)|QE(1024..1087)
#define HCP 320            // H'(256) | zb(64)
#define KTOP 64
#define EPSBN 1e-5f

typedef __attribute__((ext_vector_type(8))) short short8v;   // 8 bf16
typedef __attribute__((ext_vector_type(4))) float f32x4;

// ---------------- bf16 helpers ----------------
__device__ inline float bf2f(unsigned short u) {
    union { unsigned int i; float f; } c; c.i = ((unsigned int)u) << 16; return c.f;
}
__device__ inline unsigned short f2bf(float f) {
    union { float f; unsigned int i; } c; c.f = f;
    unsigned int r = c.i + 0x7FFFu + ((c.i >> 16) & 1u);
    return (unsigned short)(r >> 16);
}
__device__ inline void split2(float v, unsigned short& hi, unsigned short& lo) {
    hi = f2bf(v);
    lo = f2bf(v - bf2f(hi));
}
// column permutation: K old 256..511 and V old 512..767 interleave per 4-group
__device__ inline int permcol(int n) {
    if (n < 256 || n >= 768) return n;
    if (n < 512) { int l = n - 256; return 256 + ((l >> 2) << 3) + (l & 3); }
    int l = n - 512; return 256 + ((l >> 2) << 3) + 4 + (l & 3);
}

// ---------------------------------------------------------------------------
// split_x: fp32 [NN,64] -> hi/lo bf16 pair
// ---------------------------------------------------------------------------
__global__ __launch_bounds__(256) void split_x(
    const float* __restrict__ X,
    unsigned short* __restrict__ Xhi, unsigned short* __restrict__ Xlo)
{
    size_t i8 = ((size_t)blockIdx.x * 256 + threadIdx.x) * 8;
    float4 a0 = *(const float4*)(X + i8);
    float4 a1 = *(const float4*)(X + i8 + 4);
    float av[8] = {a0.x, a0.y, a0.z, a0.w, a1.x, a1.y, a1.z, a1.w};
    short8v vh, vl;
    #pragma unroll
    for (int j = 0; j < 8; j++) {
        unsigned short h, l;
        split2(av[j], h, l);
        vh[j] = (short)h; vl[j] = (short)l;
    }
    *(short8v*)(Xhi + i8) = vh;
    *(short8v*)(Xlo + i8) = vl;
}

// ---------------------------------------------------------------------------
// prep (parallelized, 65 blocks). WT rows stored at PERMUTED positions so
// C comes out with KV interleaved. bcat also permuted.
// ---------------------------------------------------------------------------
__global__ __launch_bounds__(256) void prep(
    const float* __restrict__ Wq, const float* __restrict__ bq,
    const float* __restrict__ Wk, const float* __restrict__ bk,
    const float* __restrict__ Wv, const float* __restrict__ bv,
    const float* __restrict__ Ws, const float* __restrict__ bs,
    const float* __restrict__ We, const float* __restrict__ tW,
    const float* __restrict__ Wb,
    unsigned short* __restrict__ WThi, unsigned short* __restrict__ WTlo,
    float* __restrict__ bcat,
    unsigned short* __restrict__ tWThi, unsigned short* __restrict__ tWTlo,
    float* __restrict__ Wbf, float* __restrict__ stats)
{
    const int t = threadIdx.x, b = blockIdx.x;
    if (b < 16) {
        int n = b * 64 + (t >> 2);          // OLD column index
        int cc = n & 255;
        const float* src = (n < 256) ? Wq : (n < 512) ? Wk : (n < 768) ? Wv : Ws;
        int p = permcol(n);                 // NEW row position
        int k0 = (t & 3) * 16;
        #pragma unroll
        for (int k = k0; k < k0 + 16; k++) {
            unsigned short h, l;
            split2(src[k * 256 + cc], h, l);
            WThi[p * 64 + k] = h; WTlo[p * 64 + k] = l;
        }
    } else if (b < 32) {
        int idx = (b - 16) * 256 + t;
        int k = idx >> 6, o = idx & 63;
        int h = o >> 4, f = o & 15;
        const float* wq = Wq + k * 256 + h * 64;
        const float* we = We + f * 256 + h * 64;
        float s = 0.f;
        #pragma unroll
        for (int d = 0; d < 64; d++) s += wq[d] * we[d];
        unsigned short hh, ll;
        split2(s, hh, ll);
        WThi[(1024 + o) * 64 + k] = hh; WTlo[(1024 + o) * 64 + k] = ll;
    } else if (b < 48) {
        int idx = (b - 32) * 256 + t;
        int kp = idx >> 6, n = idx & 63;
        int h = kp >> 4, f = kp & 15;
        const float* we = We + f * 256 + h * 64;
        const float* tw = tW + (h * 64) * 64 + n;
        float s = 0.f;
        #pragma unroll
        for (int d = 0; d < 64; d++) s += we[d] * tw[d * 64];
        unsigned short hh, ll;
        split2(s, hh, ll);
        tWThi[n * HCP + 256 + kp] = hh; tWTlo[n * HCP + 256 + kp] = ll;
    } else if (b < 64) {
        int base = (b - 48) * 1024 + t * 4;
        #pragma unroll
        for (int i = 0; i < 4; i++) {
            int idx = base + i;
            int n = idx >> 8, k = idx & 255;
            unsigned short h, l;
            split2(tW[k * 64 + n], h, l);
            tWThi[n * HCP + k] = h; tWTlo[n * HCP + k] = l;
        }
    } else {
        if (t < 128) stats[t] = 0.f;
        Wbf[t]       = Wb[t]       + Wb[512 + t];   // w13
        Wbf[256 + t] = Wb[256 + t] - Wb[512 + t];   // w23
        for (int c = t; c < 1024; c += 256) {
            int cc = c & 255;
            float v = (c < 256) ? bq[cc] : (c < 512) ? bk[cc] : (c < 768) ? bv[cc] : bs[cc];
            bcat[permcol(c)] = v;
        }
        if (t < 64) {
            int h = t >> 4, f = t & 15;
            const float* we = We + f * 256 + h * 64;
            float s = 0.f, sb = 0.f;
            #pragma unroll
            for (int d = 0; d < 64; d++) {
                s  += we[d] * (Wb[h * 64 + d] + Wb[512 + h * 64 + d]);
                sb += we[d] * bq[h * 64 + d];
            }
            Wbf[512 + t] = s;        // we13
            bcat[1024 + t] = sb;     // qe bias
        }
    }
}

// ---------------------------------------------------------------------------
// MFMA projection (split-bf16): C_bf16[M,1088] = A[M,64] @ W[64,1088] + bcat
// One block per 64-row chunk; A staged ONCE; loops over all 17 column tiles.
// ---------------------------------------------------------------------------
__global__ __launch_bounds__(256) void proj_mfma(
    const unsigned short* __restrict__ Ahi, const unsigned short* __restrict__ Alo,
    const unsigned short* __restrict__ WThi, const unsigned short* __restrict__ WTlo,
    const float* __restrict__ bcat, unsigned short* __restrict__ C)
{
    __shared__ unsigned short AhiL[4096], AloL[4096];   // 16 KB
    __shared__ unsigned short WhiL[4096], WloL[4096];   // 16 KB
    __shared__ float CL[64 * 68];                       // 17.4 KB
    const int t = threadIdx.x;
    const int row0 = blockIdx.x * 64;
    const int w = t >> 6, l = t & 63;
    const int lr = l & 15, lg = l >> 4, ls = l & 7;

    #pragma unroll
    for (int g = 0; g < 2; g++) {
        int idx = t * 8 + g * 2048;
        int r = idx >> 6, c = idx & 63;
        int ch = (c >> 3) ^ (r & 7);
        *(short8v*)(AhiL + r * 64 + ch * 8) =
            *(const short8v*)(Ahi + (size_t)(row0 + r) * 64 + c);
        *(short8v*)(AloL + r * 64 + ch * 8) =
            *(const short8v*)(Alo + (size_t)(row0 + r) * 64 + c);
    }

    for (int n0 = 0; n0 < NCAT; n0 += 64) {
        #pragma unroll
        for (int g = 0; g < 2; g++) {
            int idx = t * 8 + g * 2048;
            int r = idx >> 6, c = idx & 63;
            int ch = (c >> 3) ^ (r & 7);
            *(short8v*)(WhiL + r * 64 + ch * 8) =
                *(const short8v*)(WThi + (size_t)(n0 + r) * 64 + c);
            *(short8v*)(WloL + r * 64 + ch * 8) =
                *(const short8v*)(WTlo + (size_t)(n0 + r) * 64 + c);
        }
        __syncthreads();
        f32x4 acc[4] = {};
        #pragma unroll
        for (int kk = 0; kk < 2; kk++) {
            int ch = (kk * 4 + lg) ^ ls;
            short8v ah = *(short8v*)(AhiL + (w * 16 + lr) * 64 + ch * 8);
            short8v al = *(short8v*)(AloL + (w * 16 + lr) * 64 + ch * 8);
            #pragma unroll
            for (int nt = 0; nt < 4; nt++) {
                short8v bh = *(short8v*)(WhiL + (nt * 16 + lr) * 64 + ch * 8);
                short8v bl = *(short8v*)(WloL + (nt * 16 + lr) * 64 + ch * 8);
                acc[nt] = __builtin_amdgcn_mfma_f32_16x16x32_bf16(ah, bh, acc[nt], 0, 0, 0);
                acc[nt] = __builtin_amdgcn_mfma_f32_16x16x32_bf16(al, bh, acc[nt], 0, 0, 0);
                acc[nt] = __builtin_amdgcn_mfma_f32_16x16x32_bf16(ah, bl, acc[nt], 0, 0, 0);
            }
        }
        #pragma unroll
        for (int nt = 0; nt < 4; nt++)
            #pragma unroll
            for (int r = 0; r < 4; r++)
                CL[(w * 16 + lg * 4 + r) * 68 + nt * 16 + lr] = acc[nt][r];
        __syncthreads();
        {
            int r = t >> 2, cb = (t & 3) * 16;
            #pragma unroll
            for (int jj = 0; jj < 2; jj++) {
                f32x4 p0 = *(f32x4*)(CL + r * 68 + cb + jj * 8);
                f32x4 p1 = *(f32x4*)(CL + r * 68 + cb + jj * 8 + 4);
                float4 b0 = *(const float4*)(bcat + n0 + cb + jj * 8);
                float4 b1 = *(const float4*)(bcat + n0 + cb + jj * 8 + 4);
                short8v o;
                o[0] = (short)f2bf(p0[0] + b0.x); o[1] = (short)f2bf(p0[1] + b0.y);
                o[2] = (short)f2bf(p0[2] + b0.z); o[3] = (short)f2bf(p0[3] + b0.w);
                o[4] = (short)f2bf(p1[0] + b1.x); o[5] = (short)f2bf(p1[1] + b1.y);
                o[6] = (short)f2bf(p1[2] + b1.z); o[7] = (short)f2bf(p1[3] + b1.w);
                *(short8v*)(C + (size_t)(row0 + r) * NCAT + n0 + cb + jj * 8) = o;
            }
        }
        __syncthreads();
    }
}

// ---------------------------------------------------------------------------
// MFMA transform (split-bf16): T_f32[M,64] = relu(A[M,320] @ W[320,64] + b)
// ---------------------------------------------------------------------------
__global__ __launch_bounds__(256) void gemm_t(
    const unsigned short* __restrict__ Ahi, const unsigned short* __restrict__ Alo,
    const unsigned short* __restrict__ WThi, const unsigned short* __restrict__ WTlo,
    const float* __restrict__ bias, float* __restrict__ Tout,
    float* __restrict__ stats)
{
    __shared__ char smem[32768];
    unsigned short* AhiL = (unsigned short*)smem;
    unsigned short* AloL = AhiL + 4096;
    unsigned short* WhiL = AloL + 4096;
    unsigned short* WloL = WhiL + 4096;
    float* CL = (float*)smem;
    const int t = threadIdx.x;
    const int row0 = blockIdx.x * 64;
    const int w = t >> 6, l = t & 63;
    const int lr = l & 15, lg = l >> 4, ls = l & 7;
    f32x4 acc[4] = {};
    for (int kt = 0; kt < 5; kt++) {
        if (kt) __syncthreads();
        #pragma unroll
        for (int g = 0; g < 2; g++) {
            int idx = t * 8 + g * 2048;
            int r = idx >> 6, c = idx & 63;
            int ch = (c >> 3) ^ (r & 7);
            *(short8v*)(AhiL + r * 64 + ch * 8) =
                *(const short8v*)(Ahi + (size_t)(row0 + r) * HCP + kt * 64 + c);
            *(short8v*)(AloL + r * 64 + ch * 8) =
                *(const short8v*)(Alo + (size_t)(row0 + r) * HCP + kt * 64 + c);
            *(short8v*)(WhiL + r * 64 + ch * 8) =
                *(const short8v*)(WThi + r * HCP + kt * 64 + c);
            *(short8v*)(WloL + r * 64 + ch * 8) =
                *(const short8v*)(WTlo + r * HCP + kt * 64 + c);
        }
        __syncthreads();
        #pragma unroll
        for (int kk = 0; kk < 2; kk++) {
            int ch = (kk * 4 + lg) ^ ls;
            short8v ah = *(short8v*)(AhiL + (w * 16 + lr) * 64 + ch * 8);
            short8v al = *(short8v*)(AloL + (w * 16 + lr) * 64 + ch * 8);
            #pragma unroll
            for (int nt = 0; nt < 4; nt++) {
                short8v bh = *(short8v*)(WhiL + (nt * 16 + lr) * 64 + ch * 8);
                short8v bl = *(short8v*)(WloL + (nt * 16 + lr) * 64 + ch * 8);
                acc[nt] = __builtin_amdgcn_mfma_f32_16x16x32_bf16(ah, bh, acc[nt], 0, 0, 0);
                acc[nt] = __builtin_amdgcn_mfma_f32_16x16x32_bf16(al, bh, acc[nt], 0, 0, 0);
                acc[nt] = __builtin_amdgcn_mfma_f32_16x16x32_bf16(ah, bl, acc[nt], 0, 0, 0);
            }
        }
    }
    __syncthreads();
    #pragma unroll
    for (int nt = 0; nt < 4; nt++)
        #pragma unroll
        for (int r = 0; r < 4; r++)
            CL[(w * 16 + lg * 4 + r) * 68 + nt * 16 + lr] = acc[nt][r];
    __syncthreads();
    {
        int r = t >> 2, cb = (t & 3) * 16;
        #pragma unroll
        for (int jj = 0; jj < 4; jj++) {
            f32x4 p = *(f32x4*)(CL + r * 68 + cb + jj * 4);
            float4 bb = *(const float4*)(bias + cb + jj * 4);
            float4 o;
            o.x = fmaxf(p[0] + bb.x, 0.f); o.y = fmaxf(p[1] + bb.y, 0.f);
            o.z = fmaxf(p[2] + bb.z, 0.f); o.w = fmaxf(p[3] + bb.w, 0.f);
            *(float4*)(Tout + (size_t)(row0 + r) * 64 + cb + jj * 4) = o;
        }
    }
    if (t < 64) {
        float bb = bias[t];
        float s = 0.f, s2 = 0.f;
        #pragma unroll 8
        for (int r = 0; r < 64; r++) {
            float v = fmaxf(CL[r * 68 + t] + bb, 0.f);
            s += v; s2 += v * v;
        }
        atomicAdd(&stats[t], s);
        atomicAdd(&stats[64 + t], s2);
    }
}

// ---------------------------------------------------------------------------
// Attention + beta gate. 1 node per 64-lane wave, 4 ch/lane.
// KV interleaved in C: one 16B load per edge fetches K and V (halved gathers).
// ---------------------------------------------------------------------------
__global__ __launch_bounds__(256, 6) void attn_fused(
    const unsigned short* __restrict__ C,
    const float* __restrict__ Wbf,
    const int* __restrict__ srcIdx, const float* __restrict__ EA,
    unsigned short* __restrict__ Hhi, unsigned short* __restrict__ Hlo)
{
    const int t = threadIdx.x;
    const int lane = t & 63;
    const int wave = t >> 6;
    const int bid = blockIdx.x;
    const int swz = (bid & 7) * 1024 + (bid >> 3);  // 8192 blocks, XCD chunks
    const int n = swz * 4 + wave;                   // 4 nodes per block
    const int c0 = lane * 4;                        // 4 channels/lane
    const int h = lane >> 4;                        // head
    const int fi = lane & 15;                       // edge-feature index

    const unsigned short* rowN = C + (size_t)n * NCAT;
    ushort4 qv = *(const ushort4*)(rowN + c0);
    float q0 = bf2f(qv.x), q1 = bf2f(qv.y), q2 = bf2f(qv.z), q3 = bf2f(qv.w);
    float qe_l = bf2f(rowN[1024 + h * 16 + fi]);

    const int ebase = n * DEG;
    int sj = srcIdx[ebase + (lane & 7)];
    int ss[DEG];
    #pragma unroll
    for (int j = 0; j < DEG; j++) ss[j] = __shfl(sj, j);

    // batched KV + EA loads (one 16B gather per edge: K c0..c0+3 | V c0..c0+3)
    short8v kv[DEG];
    float eav[DEG];
    #pragma unroll
    for (int j = 0; j < DEG; j++) {
        kv[j] = *(const short8v*)(C + (size_t)ss[j] * NCAT + 256 + lane * 8);
        eav[j] = EA[(size_t)(ebase + j) * 16 + fi];
    }
    float alpha[DEG];
    #pragma unroll
    for (int j = 0; j < DEG; j++) {
        float d = eav[j] * qe_l
                + q0 * bf2f((unsigned short)kv[j][0]) + q1 * bf2f((unsigned short)kv[j][1])
                + q2 * bf2f((unsigned short)kv[j][2]) + q3 * bf2f((unsigned short)kv[j][3]);
        d += __shfl_xor(d, 1); d += __shfl_xor(d, 2);
        d += __shfl_xor(d, 4); d += __shfl_xor(d, 8);
        alpha[j] = d * 0.125f;                      // 1/sqrt(64)
    }
    float mx = alpha[0];
    #pragma unroll
    for (int j = 1; j < DEG; j++) mx = fmaxf(mx, alpha[j]);
    float wsum = 0.f;
    #pragma unroll
    for (int j = 0; j < DEG; j++) { alpha[j] = expf(alpha[j] - mx); wsum += alpha[j]; }
    float inv = 1.f / wsum;

    // weighted V sum from the already-loaded registers; z accumulation
    float o0 = 0.f, o1 = 0.f, o2 = 0.f, o3 = 0.f, eg = 0.f;
    #pragma unroll
    for (int j = 0; j < DEG; j++) {
        float wj = alpha[j] * inv;
        eg += wj * eav[j];
        o0 += wj * bf2f((unsigned short)kv[j][4]);
        o1 += wj * bf2f((unsigned short)kv[j][5]);
        o2 += wj * bf2f((unsigned short)kv[j][6]);
        o3 += wj * bf2f((unsigned short)kv[j][7]);
    }

    ushort4 sv = *(const ushort4*)(rowN + 768 + c0);
    float xr0 = bf2f(sv.x), xr1 = bf2f(sv.y), xr2 = bf2f(sv.z), xr3 = bf2f(sv.w);

    // beta logit: o.w13 + xr.w23 + z.we13 (we13 index == lane)
    float part = eg * Wbf[512 + lane];
    {
        f32x4 w13 = *(const f32x4*)(Wbf + c0);
        f32x4 w23 = *(const f32x4*)(Wbf + 256 + c0);
        part += o0 * w13[0] + o1 * w13[1] + o2 * w13[2] + o3 * w13[3];
        part += xr0 * w23[0] + xr1 * w23[1] + xr2 * w23[2] + xr3 * w23[3];
    }
    part += __shfl_xor(part, 1);  part += __shfl_xor(part, 2);
    part += __shfl_xor(part, 4);  part += __shfl_xor(part, 8);
    part += __shfl_xor(part, 16); part += __shfl_xor(part, 32);
    float beta = 1.f / (1.f + expf(-part));
    float omb = 1.f - beta;

    ushort4 hh, hl;
    split2(beta * xr0 + omb * o0, hh.x, hl.x);
    split2(beta * xr1 + omb * o1, hh.y, hl.y);
    split2(beta * xr2 + omb * o2, hh.z, hl.z);
    split2(beta * xr3 + omb * o3, hh.w, hl.w);
    *(ushort4*)(Hhi + (size_t)n * HCP + c0) = hh;
    *(ushort4*)(Hlo + (size_t)n * HCP + c0) = hl;

    unsigned short zh, zl;
    split2(omb * eg, zh, zl);
    Hhi[(size_t)n * HCP + 256 + lane] = zh;
    Hlo[(size_t)n * HCP + 256 + lane] = zl;
}

// ---------------------------------------------------------------------------
// BN apply: normalize + emit bf16 hi/lo; optional f32 write (pool needs it)
// ---------------------------------------------------------------------------
__global__ __launch_bounds__(256) void bn_apply(
    float* __restrict__ T, const float* __restrict__ stats,
    const float* __restrict__ g, const float* __restrict__ b,
    unsigned short* __restrict__ Thi, unsigned short* __restrict__ Tlo,
    int wf32)
{
    int i = blockIdx.x * 256 + threadIdx.x;
    int c = i & 63;
    float mean = stats[c] * (1.f / NN);
    float var  = stats[64 + c] * (1.f / NN) - mean * mean;
    float v = T[i];
    float r = g[c] * (v - mean) * rsqrtf(var + EPSBN) + b[c];
    if (wf32) T[i] = r;
    unsigned short h, l;
    split2(r, h, l);
    Thi[i] = h; Tlo[i] = l;
}

// ---------------------------------------------------------------------------
// TopK pooling + readout + MLP head. One block (128 threads) per graph.
// ---------------------------------------------------------------------------
__global__ __launch_bounds__(128) void pool_mlp(
    const float* __restrict__ Hn, const float* __restrict__ pw,
    const float* __restrict__ W1, const float* __restrict__ b1,
    const float* __restrict__ W2, const float* __restrict__ b2,
    const float* __restrict__ W3, const float* __restrict__ b3,
    float* __restrict__ out)
{
    __shared__ float sh[128][65];
    __shared__ float spw[64];
    __shared__ float sc[128];
    __shared__ float sscale[128];
    __shared__ int   skeep[128];
    __shared__ float rmax[2][64], rsum[2][64];
    __shared__ float srep[128];
    __shared__ float sh1[256];
    __shared__ float sh2[128];
    __shared__ float wred[2];
    const int g = blockIdx.x, t = threadIdx.x;

    for (int i = t; i < 128 * 64; i += 128) sh[i >> 6][i & 63] = Hn[(size_t)g * 128 * 64 + i];
    if (t < 64) spw[t] = pw[t];
    __syncthreads();

    float nw = 0.f;
    #pragma unroll
    for (int i = 0; i < 64; i++) { float w = spw[i]; nw += w * w; }
    float invn = rsqrtf(nw);

    float s = 0.f;
    #pragma unroll
    for (int i = 0; i < 64; i++) s += sh[t][i] * spw[i];
    s *= invn;
    sc[t] = s;
    __syncthreads();

    int rank = 0;
    for (int m = 0; m < 128; m++) {
        float sm = sc[m];
        rank += (sm > s) || (sm == s && m < t);
    }
    skeep[t] = (rank < KTOP);
    sscale[t] = tanhf(s);
    __syncthreads();

    {
        int c = t & 63, half = t >> 6;
        float mxv = -1e30f, sm = 0.f;
        for (int r = half * 64; r < half * 64 + 64; r++) {
            if (skeep[r]) {
                float v = sh[r][c] * sscale[r];
                mxv = fmaxf(mxv, v); sm += v;
            }
        }
        rmax[half][c] = mxv; rsum[half][c] = sm;
    }
    __syncthreads();
    if (t < 64) {
        srep[t] = fmaxf(rmax[0][t], rmax[1][t]);
        srep[64 + t] = (rsum[0][t] + rsum[1][t]) * (1.f / KTOP);
    }
    __syncthreads();

    #pragma unroll
    for (int jj = 0; jj < 2; jj++) {
        int j = t + jj * 128;
        float a = b1[j];
        for (int c2 = 0; c2 < 128; c2++) a += srep[c2] * W1[c2 * 256 + j];
        sh1[j] = fmaxf(a, 0.f);
    }
    __syncthreads();
    {
        float a = b2[t];
        for (int c2 = 0; c2 < 256; c2++) a += sh1[c2] * W2[c2 * 128 + t];
        sh2[t] = fmaxf(a, 0.f);
    }
    __syncthreads();
    float p = sh2[t] * W3[t];
    p += __shfl_xor(p, 1);  p += __shfl_xor(p, 2);  p += __shfl_xor(p, 4);
    p += __shfl_xor(p, 8);  p += __shfl_xor(p, 16); p += __shfl_xor(p, 32);
    if ((t & 63) == 0) wred[t >> 6] = p;
    __syncthreads();
    if (t == 0) out[g] = wred[0] + wred[1] + b3[0];
}

// ---------------------------------------------------------------------------
extern "C" void kernel_launch(void* const* d_in, const int* in_sizes, int n_in,
                              void* d_out, int out_size, void* d_ws, size_t ws_size,
                              hipStream_t stream)
{
    const float* x    = (const float*)d_in[0];
    const int*   ei   = (const int*)  d_in[1];
    const float* ea   = (const float*)d_in[2];
    const int*   srcI = ei;
    const float* Wq1 = (const float*)d_in[4];  const float* bq1 = (const float*)d_in[5];
    const float* Wk1 = (const float*)d_in[6];  const float* bk1 = (const float*)d_in[7];
    const float* Wv1 = (const float*)d_in[8];  const float* bv1 = (const float*)d_in[9];
    const float* We1 = (const float*)d_in[10];
    const float* Ws1 = (const float*)d_in[11]; const float* bs1 = (const float*)d_in[12];
    const float* Wb1 = (const float*)d_in[13];
    const float* t1W = (const float*)d_in[14]; const float* t1b = (const float*)d_in[15];
    const float* g1  = (const float*)d_in[16]; const float* be1 = (const float*)d_in[17];
    const float* Wq2 = (const float*)d_in[18]; const float* bq2 = (const float*)d_in[19];
    const float* Wk2 = (const float*)d_in[20]; const float* bk2 = (const float*)d_in[21];
    const float* Wv2 = (const float*)d_in[22]; const float* bv2 = (const float*)d_in[23];
    const float* We2 = (const float*)d_in[24];
    const float* Ws2 = (const float*)d_in[25]; const float* bs2 = (const float*)d_in[26];
    const float* Wb2 = (const float*)d_in[27];
    const float* t2W = (const float*)d_in[28]; const float* t2b = (const float*)d_in[29];
    const float* g2  = (const float*)d_in[30]; const float* be2 = (const float*)d_in[31];
    const float* pw  = (const float*)d_in[32];
    const float* l1W = (const float*)d_in[33]; const float* l1b = (const float*)d_in[34];
    const float* l2W = (const float*)d_in[35]; const float* l2b = (const float*)d_in[36];
    const float* l3W = (const float*)d_in[37]; const float* l3b = (const float*)d_in[38];

    char* ws = (char*)d_ws;
    unsigned short* C   = (unsigned short*)ws;                     // [NN,1088] bf16
    unsigned short* Hhi = (unsigned short*)(ws + (size_t)NN * NCAT * 2); // [NN,320]
    unsigned short* Hlo = Hhi + (size_t)NN * HCP;
    float* bT    = (float*)(Hlo + (size_t)NN * HCP);               // [NN,64] f32
    unsigned short* bThi = (unsigned short*)(bT + (size_t)NN * 64);
    unsigned short* bTlo = bThi + (size_t)NN * 64;
    unsigned short* Xhi  = bTlo + (size_t)NN * 64;
    unsigned short* Xlo  = Xhi + (size_t)NN * 64;
    float* bcat  = (float*)(Xlo + (size_t)NN * 64);                // [1088]
    float* stats = bcat + NCAT;                                    // [128]
    float* Wbf   = stats + 128;                                    // [576]
    unsigned short* WThi  = (unsigned short*)(Wbf + 576);          // [1088][64]
    unsigned short* WTlo  = WThi + (size_t)NCAT * 64;
    unsigned short* tWThi = WTlo + (size_t)NCAT * 64;              // [64][320]
    unsigned short* tWTlo = tWThi + 64 * HCP;

    const dim3 blk(256);

    // ---- layer 1 ----
    split_x<<<NN * 64 / (256 * 8), blk, 0, stream>>>(x, Xhi, Xlo);
    prep<<<65, blk, 0, stream>>>(Wq1, bq1, Wk1, bk1, Wv1, bv1, Ws1, bs1, We1, t1W, Wb1,
                                 WThi, WTlo, bcat, tWThi, tWTlo, Wbf, stats);
    proj_mfma<<<512, blk, 0, stream>>>(Xhi, Xlo, WThi, WTlo, bcat, C);
    attn_fused<<<NN / 4, blk, 0, stream>>>(C, Wbf, srcI, ea, Hhi, Hlo);
    gemm_t<<<512, blk, 0, stream>>>(Hhi, Hlo, tWThi, tWTlo, t1b, bT, stats);
    bn_apply<<<NN * 64 / 256, blk, 0, stream>>>(bT, stats, g1, be1, bThi, bTlo, 0);

    // ---- layer 2 ----
    prep<<<65, blk, 0, stream>>>(Wq2, bq2, Wk2, bk2, Wv2, bv2, Ws2, bs2, We2, t2W, Wb2,
                                 WThi, WTlo, bcat, tWThi, tWTlo, Wbf, stats);
    proj_mfma<<<512, blk, 0, stream>>>(bThi, bTlo, WThi, WTlo, bcat, C);
    attn_fused<<<NN / 4, blk, 0, stream>>>(C, Wbf, srcI, ea, Hhi, Hlo);
    gemm_t<<<512, blk, 0, stream>>>(Hhi, Hlo, tWThi, tWTlo, t2b, bT, stats);
    bn_apply<<<NN * 64 / 256, blk, 0, stream>>>(bT, stats, g2, be2, bThi, bTlo, 1);

    // ---- pooling + head ----
    pool_mlp<<<NG, 128, 0, stream>>>(bT, pw, l1W, l1b, l2W, l2b, l3W, l3b,
                                     (float*)d_out);
}

// Round 12
// 201.931 us; speedup vs baseline: 1.0932x; 1.0932x over previous
//
#include <hip/hip_runtime.h>
#include <math.h>

#define NN 32768
#define NG 256
#define DEG 8
#define HC 256
#define NCAT 1088          // Q(256)|KV interleaved(512)|S(768..1023)|QE(1024..1087)
#define HCP 320            // H'(256) | zb(64)
#define KTOP 64
#define EPSBN 1e-5f

typedef __attribute__((ext_vector_type(8))) short short8v;   // 8 bf16
typedef __attribute__((ext_vector_type(4))) float f32x4;

// ---------------- bf16 helpers ----------------
__device__ inline float bf2f(unsigned short u) {
    union { unsigned int i; float f; } c; c.i = ((unsigned int)u) << 16; return c.f;
}
__device__ inline unsigned short f2bf(float f) {
    union { float f; unsigned int i; } c; c.f = f;
    unsigned int r = c.i + 0x7FFFu + ((c.i >> 16) & 1u);
    return (unsigned short)(r >> 16);
}
// hi = RNE bf16; lo = truncated residual (2^-17-relative error, negligible)
__device__ inline void split2(float v, unsigned short& hi, unsigned short& lo) {
    hi = f2bf(v);
    union { float f; unsigned int i; } c; c.f = v - bf2f(hi);
    lo = (unsigned short)(c.i >> 16);
}
// column permutation: K old 256..511 and V old 512..767 interleave per 4-group
__device__ inline int permcol(int n) {
    if (n < 256 || n >= 768) return n;
    if (n < 512) { int l = n - 256; return 256 + ((l >> 2) << 3) + (l & 3); }
    int l = n - 512; return 256 + ((l >> 2) << 3) + 4 + (l & 3);
}

// ---------------------------------------------------------------------------
// prep device body (65 logical blocks per layer)
// ---------------------------------------------------------------------------
__device__ void prep_dev(int b, int t,
    const float* __restrict__ Wq, const float* __restrict__ bq,
    const float* __restrict__ Wk, const float* __restrict__ bk,
    const float* __restrict__ Wv, const float* __restrict__ bv,
    const float* __restrict__ Ws, const float* __restrict__ bs,
    const float* __restrict__ We, const float* __restrict__ tW,
    const float* __restrict__ Wb,
    unsigned short* __restrict__ WThi, unsigned short* __restrict__ WTlo,
    float* __restrict__ bcat,
    unsigned short* __restrict__ tWThi, unsigned short* __restrict__ tWTlo,
    float* __restrict__ Wbf, float* __restrict__ stats)
{
    if (b < 16) {
        int n = b * 64 + (t >> 2);          // OLD column index
        int cc = n & 255;
        const float* src = (n < 256) ? Wq : (n < 512) ? Wk : (n < 768) ? Wv : Ws;
        int p = permcol(n);                 // NEW row position
        int k0 = (t & 3) * 16;
        #pragma unroll
        for (int k = k0; k < k0 + 16; k++) {
            unsigned short h, l;
            split2(src[k * 256 + cc], h, l);
            WThi[p * 64 + k] = h; WTlo[p * 64 + k] = l;
        }
    } else if (b < 32) {
        int idx = (b - 16) * 256 + t;
        int k = idx >> 6, o = idx & 63;
        int h = o >> 4, f = o & 15;
        const float* wq = Wq + k * 256 + h * 64;
        const float* we = We + f * 256 + h * 64;
        float s = 0.f;
        #pragma unroll
        for (int d = 0; d < 64; d++) s += wq[d] * we[d];
        unsigned short hh, ll;
        split2(s, hh, ll);
        WThi[(1024 + o) * 64 + k] = hh; WTlo[(1024 + o) * 64 + k] = ll;
    } else if (b < 48) {
        int idx = (b - 32) * 256 + t;
        int kp = idx >> 6, n = idx & 63;
        int h = kp >> 4, f = kp & 15;
        const float* we = We + f * 256 + h * 64;
        const float* tw = tW + (h * 64) * 64 + n;
        float s = 0.f;
        #pragma unroll
        for (int d = 0; d < 64; d++) s += we[d] * tw[d * 64];
        unsigned short hh, ll;
        split2(s, hh, ll);
        tWThi[n * HCP + 256 + kp] = hh; tWTlo[n * HCP + 256 + kp] = ll;
    } else if (b < 64) {
        int base = (b - 48) * 1024 + t * 4;
        #pragma unroll
        for (int i = 0; i < 4; i++) {
            int idx = base + i;
            int n = idx >> 8, k = idx & 255;
            unsigned short h, l;
            split2(tW[k * 64 + n], h, l);
            tWThi[n * HCP + k] = h; tWTlo[n * HCP + k] = l;
        }
    } else {
        if (t < 128) stats[t] = 0.f;
        Wbf[t]       = Wb[t]       + Wb[512 + t];   // w13
        Wbf[256 + t] = Wb[256 + t] - Wb[512 + t];   // w23
        for (int c = t; c < 1024; c += 256) {
            int cc = c & 255;
            float v = (c < 256) ? bq[cc] : (c < 512) ? bk[cc] : (c < 768) ? bv[cc] : bs[cc];
            bcat[permcol(c)] = v;
        }
        if (t < 64) {
            int h = t >> 4, f = t & 15;
            const float* we = We + f * 256 + h * 64;
            float s = 0.f, sb = 0.f;
            #pragma unroll
            for (int d = 0; d < 64; d++) {
                s  += we[d] * (Wb[h * 64 + d] + Wb[512 + h * 64 + d]);
                sb += we[d] * bq[h * 64 + d];
            }
            Wbf[512 + t] = s;        // we13
            bcat[1024 + t] = sb;     // qe bias
        }
    }
}

__global__ __launch_bounds__(256) void prep_all(
    const float* Wq1, const float* bq1, const float* Wk1, const float* bk1,
    const float* Wv1, const float* bv1, const float* Ws1, const float* bs1,
    const float* We1, const float* t1W, const float* Wb1,
    unsigned short* WThi1, unsigned short* WTlo1, float* bcat1,
    unsigned short* tWThi1, unsigned short* tWTlo1, float* Wbf1, float* stats1,
    const float* Wq2, const float* bq2, const float* Wk2, const float* bk2,
    const float* Wv2, const float* bv2, const float* Ws2, const float* bs2,
    const float* We2, const float* t2W, const float* Wb2,
    unsigned short* WThi2, unsigned short* WTlo2, float* bcat2,
    unsigned short* tWThi2, unsigned short* tWTlo2, float* Wbf2, float* stats2)
{
    const int b = blockIdx.x, t = threadIdx.x;
    if (b < 65)
        prep_dev(b, t, Wq1, bq1, Wk1, bk1, Wv1, bv1, Ws1, bs1, We1, t1W, Wb1,
                 WThi1, WTlo1, bcat1, tWThi1, tWTlo1, Wbf1, stats1);
    else
        prep_dev(b - 65, t, Wq2, bq2, Wk2, bk2, Wv2, bv2, Ws2, bs2, We2, t2W, Wb2,
                 WThi2, WTlo2, bcat2, tWThi2, tWTlo2, Wbf2, stats2);
}

// ---------------------------------------------------------------------------
// MFMA projection (split-bf16): C_bf16[M,1088] = A'[M,64] @ W[64,1088] + bcat
// A' = A (stats==null) or BN(A) (stats given); split performed inline while
// staging. One block per 64-row chunk; A staged once; loops 17 column tiles.
// ---------------------------------------------------------------------------
__global__ __launch_bounds__(256) void proj_mfma(
    const float* __restrict__ A, const float* __restrict__ stats,
    const float* __restrict__ gbn, const float* __restrict__ bbn,
    const unsigned short* __restrict__ WThi, const unsigned short* __restrict__ WTlo,
    const float* __restrict__ bcat, unsigned short* __restrict__ C)
{
    __shared__ unsigned short AhiL[4096], AloL[4096];   // 16 KB
    __shared__ unsigned short WhiL[4096], WloL[4096];   // 16 KB
    __shared__ float CL[64 * 68];                       // 17.4 KB
    __shared__ float scl[64], sft[64];
    const int t = threadIdx.x;
    const int row0 = blockIdx.x * 64;
    const int w = t >> 6, l = t & 63;
    const int lr = l & 15, lg = l >> 4, ls = l & 7;

    if (t < 64) {
        if (stats) {
            float mean = stats[t] * (1.f / NN);
            float var  = stats[64 + t] * (1.f / NN) - mean * mean;
            float s = gbn[t] * rsqrtf(var + EPSBN);
            scl[t] = s; sft[t] = bbn[t] - mean * s;
        } else { scl[t] = 1.f; sft[t] = 0.f; }
    }
    __syncthreads();

    #pragma unroll
    for (int g = 0; g < 2; g++) {
        int idx = t * 8 + g * 2048;
        int r = idx >> 6, c = idx & 63;
        int ch = (c >> 3) ^ (r & 7);
        float4 a0 = *(const float4*)(A + (size_t)(row0 + r) * 64 + c);
        float4 a1 = *(const float4*)(A + (size_t)(row0 + r) * 64 + c + 4);
        float av[8] = {a0.x, a0.y, a0.z, a0.w, a1.x, a1.y, a1.z, a1.w};
        short8v vh, vl;
        #pragma unroll
        for (int j = 0; j < 8; j++) {
            float v = av[j] * scl[c + j] + sft[c + j];
            unsigned short h2, l2;
            split2(v, h2, l2);
            vh[j] = (short)h2; vl[j] = (short)l2;
        }
        *(short8v*)(AhiL + r * 64 + ch * 8) = vh;
        *(short8v*)(AloL + r * 64 + ch * 8) = vl;
    }

    for (int n0 = 0; n0 < NCAT; n0 += 64) {
        #pragma unroll
        for (int g = 0; g < 2; g++) {
            int idx = t * 8 + g * 2048;
            int r = idx >> 6, c = idx & 63;
            int ch = (c >> 3) ^ (r & 7);
            *(short8v*)(WhiL + r * 64 + ch * 8) =
                *(const short8v*)(WThi + (size_t)(n0 + r) * 64 + c);
            *(short8v*)(WloL + r * 64 + ch * 8) =
                *(const short8v*)(WTlo + (size_t)(n0 + r) * 64 + c);
        }
        __syncthreads();
        f32x4 acc[4] = {};
        #pragma unroll
        for (int kk = 0; kk < 2; kk++) {
            int ch = (kk * 4 + lg) ^ ls;
            short8v ah = *(short8v*)(AhiL + (w * 16 + lr) * 64 + ch * 8);
            short8v al = *(short8v*)(AloL + (w * 16 + lr) * 64 + ch * 8);
            #pragma unroll
            for (int nt = 0; nt < 4; nt++) {
                short8v bh = *(short8v*)(WhiL + (nt * 16 + lr) * 64 + ch * 8);
                short8v bl = *(short8v*)(WloL + (nt * 16 + lr) * 64 + ch * 8);
                acc[nt] = __builtin_amdgcn_mfma_f32_16x16x32_bf16(ah, bh, acc[nt], 0, 0, 0);
                acc[nt] = __builtin_amdgcn_mfma_f32_16x16x32_bf16(al, bh, acc[nt], 0, 0, 0);
                acc[nt] = __builtin_amdgcn_mfma_f32_16x16x32_bf16(ah, bl, acc[nt], 0, 0, 0);
            }
        }
        #pragma unroll
        for (int nt = 0; nt < 4; nt++)
            #pragma unroll
            for (int r = 0; r < 4; r++)
                CL[(w * 16 + lg * 4 + r) * 68 + nt * 16 + lr] = acc[nt][r];
        __syncthreads();
        {
            int r = t >> 2, cb = (t & 3) * 16;
            #pragma unroll
            for (int jj = 0; jj < 2; jj++) {
                f32x4 p0 = *(f32x4*)(CL + r * 68 + cb + jj * 8);
                f32x4 p1 = *(f32x4*)(CL + r * 68 + cb + jj * 8 + 4);
                float4 b0 = *(const float4*)(bcat + n0 + cb + jj * 8);
                float4 b1 = *(const float4*)(bcat + n0 + cb + jj * 8 + 4);
                short8v o;
                o[0] = (short)f2bf(p0[0] + b0.x); o[1] = (short)f2bf(p0[1] + b0.y);
                o[2] = (short)f2bf(p0[2] + b0.z); o[3] = (short)f2bf(p0[3] + b0.w);
                o[4] = (short)f2bf(p1[0] + b1.x); o[5] = (short)f2bf(p1[1] + b1.y);
                o[6] = (short)f2bf(p1[2] + b1.z); o[7] = (short)f2bf(p1[3] + b1.w);
                *(short8v*)(C + (size_t)(row0 + r) * NCAT + n0 + cb + jj * 8) = o;
            }
        }
        __syncthreads();
    }
}

// ---------------------------------------------------------------------------
// MFMA transform (split-bf16): T_f32[M,64] = relu(A[M,320] @ W[320,64] + b)
// Epilogue accumulates BN column stats via atomics.
// ---------------------------------------------------------------------------
__global__ __launch_bounds__(256) void gemm_t(
    const unsigned short* __restrict__ Ahi, const unsigned short* __restrict__ Alo,
    const unsigned short* __restrict__ WThi, const unsigned short* __restrict__ WTlo,
    const float* __restrict__ bias, float* __restrict__ Tout,
    float* __restrict__ stats)
{
    __shared__ char smem[32768];
    unsigned short* AhiL = (unsigned short*)smem;
    unsigned short* AloL = AhiL + 4096;
    unsigned short* WhiL = AloL + 4096;
    unsigned short* WloL = WhiL + 4096;
    float* CL = (float*)smem;
    const int t = threadIdx.x;
    const int row0 = blockIdx.x * 64;
    const int w = t >> 6, l = t & 63;
    const int lr = l & 15, lg = l >> 4, ls = l & 7;
    f32x4 acc[4] = {};
    for (int kt = 0; kt < 5; kt++) {
        if (kt) __syncthreads();
        #pragma unroll
        for (int g = 0; g < 2; g++) {
            int idx = t * 8 + g * 2048;
            int r = idx >> 6, c = idx & 63;
            int ch = (c >> 3) ^ (r & 7);
            *(short8v*)(AhiL + r * 64 + ch * 8) =
                *(const short8v*)(Ahi + (size_t)(row0 + r) * HCP + kt * 64 + c);
            *(short8v*)(AloL + r * 64 + ch * 8) =
                *(const short8v*)(Alo + (size_t)(row0 + r) * HCP + kt * 64 + c);
            *(short8v*)(WhiL + r * 64 + ch * 8) =
                *(const short8v*)(WThi + r * HCP + kt * 64 + c);
            *(short8v*)(WloL + r * 64 + ch * 8) =
                *(const short8v*)(WTlo + r * HCP + kt * 64 + c);
        }
        __syncthreads();
        #pragma unroll
        for (int kk = 0; kk < 2; kk++) {
            int ch = (kk * 4 + lg) ^ ls;
            short8v ah = *(short8v*)(AhiL + (w * 16 + lr) * 64 + ch * 8);
            short8v al = *(short8v*)(AloL + (w * 16 + lr) * 64 + ch * 8);
            #pragma unroll
            for (int nt = 0; nt < 4; nt++) {
                short8v bh = *(short8v*)(WhiL + (nt * 16 + lr) * 64 + ch * 8);
                short8v bl = *(short8v*)(WloL + (nt * 16 + lr) * 64 + ch * 8);
                acc[nt] = __builtin_amdgcn_mfma_f32_16x16x32_bf16(ah, bh, acc[nt], 0, 0, 0);
                acc[nt] = __builtin_amdgcn_mfma_f32_16x16x32_bf16(al, bh, acc[nt], 0, 0, 0);
                acc[nt] = __builtin_amdgcn_mfma_f32_16x16x32_bf16(ah, bl, acc[nt], 0, 0, 0);
            }
        }
    }
    __syncthreads();
    #pragma unroll
    for (int nt = 0; nt < 4; nt++)
        #pragma unroll
        for (int r = 0; r < 4; r++)
            CL[(w * 16 + lg * 4 + r) * 68 + nt * 16 + lr] = acc[nt][r];
    __syncthreads();
    {
        int r = t >> 2, cb = (t & 3) * 16;
        #pragma unroll
        for (int jj = 0; jj < 4; jj++) {
            f32x4 p = *(f32x4*)(CL + r * 68 + cb + jj * 4);
            float4 bb = *(const float4*)(bias + cb + jj * 4);
            float4 o;
            o.x = fmaxf(p[0] + bb.x, 0.f); o.y = fmaxf(p[1] + bb.y, 0.f);
            o.z = fmaxf(p[2] + bb.z, 0.f); o.w = fmaxf(p[3] + bb.w, 0.f);
            *(float4*)(Tout + (size_t)(row0 + r) * 64 + cb + jj * 4) = o;
        }
    }
    if (t < 64) {
        float bb = bias[t];
        float s = 0.f, s2 = 0.f;
        #pragma unroll 8
        for (int r = 0; r < 64; r++) {
            float v = fmaxf(CL[r * 68 + t] + bb, 0.f);
            s += v; s2 += v * v;
        }
        atomicAdd(&stats[t], s);
        atomicAdd(&stats[64 + t], s2);
    }
}

// ---------------------------------------------------------------------------
// Attention + beta gate. 1 node per 64-lane wave, 4 ch/lane.
// KV interleaved in C: one 16B load per edge fetches K and V.
// ---------------------------------------------------------------------------
__global__ __launch_bounds__(256, 6) void attn_fused(
    const unsigned short* __restrict__ C,
    const float* __restrict__ Wbf,
    const int* __restrict__ srcIdx, const float* __restrict__ EA,
    unsigned short* __restrict__ Hhi, unsigned short* __restrict__ Hlo)
{
    const int t = threadIdx.x;
    const int lane = t & 63;
    const int wave = t >> 6;
    const int bid = blockIdx.x;
    const int swz = (bid & 7) * 1024 + (bid >> 3);  // 8192 blocks, XCD chunks
    const int n = swz * 4 + wave;                   // 4 nodes per block
    const int c0 = lane * 4;                        // 4 channels/lane
    const int h = lane >> 4;                        // head
    const int fi = lane & 15;                       // edge-feature index

    const unsigned short* rowN = C + (size_t)n * NCAT;
    ushort4 qv = *(const ushort4*)(rowN + c0);
    float q0 = bf2f(qv.x), q1 = bf2f(qv.y), q2 = bf2f(qv.z), q3 = bf2f(qv.w);
    float qe_l = bf2f(rowN[1024 + h * 16 + fi]);

    const int ebase = n * DEG;
    int sj = srcIdx[ebase + (lane & 7)];
    int ss[DEG];
    #pragma unroll
    for (int j = 0; j < DEG; j++) ss[j] = __shfl(sj, j);

    // batched KV + EA loads (one 16B gather per edge: K c0..c0+3 | V c0..c0+3)
    short8v kv[DEG];
    float eav[DEG];
    #pragma unroll
    for (int j = 0; j < DEG; j++) {
        kv[j] = *(const short8v*)(C + (size_t)ss[j] * NCAT + 256 + lane * 8);
        eav[j] = EA[(size_t)(ebase + j) * 16 + fi];
    }
    float alpha[DEG];
    #pragma unroll
    for (int j = 0; j < DEG; j++) {
        float d = eav[j] * qe_l
                + q0 * bf2f((unsigned short)kv[j][0]) + q1 * bf2f((unsigned short)kv[j][1])
                + q2 * bf2f((unsigned short)kv[j][2]) + q3 * bf2f((unsigned short)kv[j][3]);
        d += __shfl_xor(d, 1); d += __shfl_xor(d, 2);
        d += __shfl_xor(d, 4); d += __shfl_xor(d, 8);
        alpha[j] = d * 0.125f;                      // 1/sqrt(64)
    }
    float mx = alpha[0];
    #pragma unroll
    for (int j = 1; j < DEG; j++) mx = fmaxf(mx, alpha[j]);
    float wsum = 0.f;
    #pragma unroll
    for (int j = 0; j < DEG; j++) { alpha[j] = expf(alpha[j] - mx); wsum += alpha[j]; }
    float inv = 1.f / wsum;

    // weighted V sum from the already-loaded registers; z accumulation
    float o0 = 0.f, o1 = 0.f, o2 = 0.f, o3 = 0.f, eg = 0.f;
    #pragma unroll
    for (int j = 0; j < DEG; j++) {
        float wj = alpha[j] * inv;
        eg += wj * eav[j];
        o0 += wj * bf2f((unsigned short)kv[j][4]);
        o1 += wj * bf2f((unsigned short)kv[j][5]);
        o2 += wj * bf2f((unsigned short)kv[j][6]);
        o3 += wj * bf2f((unsigned short)kv[j][7]);
    }

    ushort4 sv = *(const ushort4*)(rowN + 768 + c0);
    float xr0 = bf2f(sv.x), xr1 = bf2f(sv.y), xr2 = bf2f(sv.z), xr3 = bf2f(sv.w);

    // beta logit: o.w13 + xr.w23 + z.we13 (we13 index == lane)
    float part = eg * Wbf[512 + lane];
    {
        f32x4 w13 = *(const f32x4*)(Wbf + c0);
        f32x4 w23 = *(const f32x4*)(Wbf + 256 + c0);
        part += o0 * w13[0] + o1 * w13[1] + o2 * w13[2] + o3 * w13[3];
        part += xr0 * w23[0] + xr1 * w23[1] + xr2 * w23[2] + xr3 * w23[3];
    }
    part += __shfl_xor(part, 1);  part += __shfl_xor(part, 2);
    part += __shfl_xor(part, 4);  part += __shfl_xor(part, 8);
    part += __shfl_xor(part, 16); part += __shfl_xor(part, 32);
    float beta = 1.f / (1.f + expf(-part));
    float omb = 1.f - beta;

    ushort4 hh, hl;
    split2(beta * xr0 + omb * o0, hh.x, hl.x);
    split2(beta * xr1 + omb * o1, hh.y, hl.y);
    split2(beta * xr2 + omb * o2, hh.z, hl.z);
    split2(beta * xr3 + omb * o3, hh.w, hl.w);
    *(ushort4*)(Hhi + (size_t)n * HCP + c0) = hh;
    *(ushort4*)(Hlo + (size_t)n * HCP + c0) = hl;

    unsigned short zh, zl;
    split2(omb * eg, zh, zl);
    Hhi[(size_t)n * HCP + 256 + lane] = zh;
    Hlo[(size_t)n * HCP + 256 + lane] = zl;
}

// ---------------------------------------------------------------------------
// TopK pooling + readout + MLP head. BN applied inline from stats.
// ---------------------------------------------------------------------------
__global__ __launch_bounds__(128) void pool_mlp(
    const float* __restrict__ Hn, const float* __restrict__ stats,
    const float* __restrict__ gbn, const float* __restrict__ bbn,
    const float* __restrict__ pw,
    const float* __restrict__ W1, const float* __restrict__ b1,
    const float* __restrict__ W2, const float* __restrict__ b2,
    const float* __restrict__ W3, const float* __restrict__ b3,
    float* __restrict__ out)
{
    __shared__ float sh[128][65];
    __shared__ float spw[64];
    __shared__ float sc[128];
    __shared__ float sscale[128];
    __shared__ int   skeep[128];
    __shared__ float rmax[2][64], rsum[2][64];
    __shared__ float srep[128];
    __shared__ float sh1[256];
    __shared__ float sh2[128];
    __shared__ float wred[2];
    __shared__ float scl[64], sft[64];
    const int g = blockIdx.x, t = threadIdx.x;

    if (t < 64) {
        float mean = stats[t] * (1.f / NN);
        float var  = stats[64 + t] * (1.f / NN) - mean * mean;
        float s = gbn[t] * rsqrtf(var + EPSBN);
        scl[t] = s; sft[t] = bbn[t] - mean * s;
        spw[t] = pw[t];
    }
    __syncthreads();
    for (int i = t; i < 128 * 64; i += 128) {
        int c = i & 63;
        sh[i >> 6][c] = Hn[(size_t)g * 128 * 64 + i] * scl[c] + sft[c];
    }
    __syncthreads();

    float nw = 0.f;
    #pragma unroll
    for (int i = 0; i < 64; i++) { float w = spw[i]; nw += w * w; }
    float invn = rsqrtf(nw);

    float s = 0.f;
    #pragma unroll
    for (int i = 0; i < 64; i++) s += sh[t][i] * spw[i];
    s *= invn;
    sc[t] = s;
    __syncthreads();

    int rank = 0;
    for (int m = 0; m < 128; m++) {
        float sm = sc[m];
        rank += (sm > s) || (sm == s && m < t);
    }
    skeep[t] = (rank < KTOP);
    sscale[t] = tanhf(s);
    __syncthreads();

    {
        int c = t & 63, half = t >> 6;
        float mxv = -1e30f, sm = 0.f;
        for (int r = half * 64; r < half * 64 + 64; r++) {
            if (skeep[r]) {
                float v = sh[r][c] * sscale[r];
                mxv = fmaxf(mxv, v); sm += v;
            }
        }
        rmax[half][c] = mxv; rsum[half][c] = sm;
    }
    __syncthreads();
    if (t < 64) {
        srep[t] = fmaxf(rmax[0][t], rmax[1][t]);
        srep[64 + t] = (rsum[0][t] + rsum[1][t]) * (1.f / KTOP);
    }
    __syncthreads();

    #pragma unroll
    for (int jj = 0; jj < 2; jj++) {
        int j = t + jj * 128;
        float a = b1[j];
        for (int c2 = 0; c2 < 128; c2++) a += srep[c2] * W1[c2 * 256 + j];
        sh1[j] = fmaxf(a, 0.f);
    }
    __syncthreads();
    {
        float a = b2[t];
        for (int c2 = 0; c2 < 256; c2++) a += sh1[c2] * W2[c2 * 128 + t];
        sh2[t] = fmaxf(a, 0.f);
    }
    __syncthreads();
    float p = sh2[t] * W3[t];
    p += __shfl_xor(p, 1);  p += __shfl_xor(p, 2);  p += __shfl_xor(p, 4);
    p += __shfl_xor(p, 8);  p += __shfl_xor(p, 16); p += __shfl_xor(p, 32);
    if ((t & 63) == 0) wred[t >> 6] = p;
    __syncthreads();
    if (t == 0) out[g] = wred[0] + wred[1] + b3[0];
}

// ---------------------------------------------------------------------------
extern "C" void kernel_launch(void* const* d_in, const int* in_sizes, int n_in,
                              void* d_out, int out_size, void* d_ws, size_t ws_size,
                              hipStream_t stream)
{
    const float* x    = (const float*)d_in[0];
    const int*   ei   = (const int*)  d_in[1];
    const float* ea   = (const float*)d_in[2];
    const int*   srcI = ei;
    const float* Wq1 = (const float*)d_in[4];  const float* bq1 = (const float*)d_in[5];
    const float* Wk1 = (const float*)d_in[6];  const float* bk1 = (const float*)d_in[7];
    const float* Wv1 = (const float*)d_in[8];  const float* bv1 = (const float*)d_in[9];
    const float* We1 = (const float*)d_in[10];
    const float* Ws1 = (const float*)d_in[11]; const float* bs1 = (const float*)d_in[12];
    const float* Wb1 = (const float*)d_in[13];
    const float* t1W = (const float*)d_in[14]; const float* t1b = (const float*)d_in[15];
    const float* g1  = (const float*)d_in[16]; const float* be1 = (const float*)d_in[17];
    const float* Wq2 = (const float*)d_in[18]; const float* bq2 = (const float*)d_in[19];
    const float* Wk2 = (const float*)d_in[20]; const float* bk2 = (const float*)d_in[21];
    const float* Wv2 = (const float*)d_in[22]; const float* bv2 = (const float*)d_in[23];
    const float* We2 = (const float*)d_in[24];
    const float* Ws2 = (const float*)d_in[25]; const float* bs2 = (const float*)d_in[26];
    const float* Wb2 = (const float*)d_in[27];
    const float* t2W = (const float*)d_in[28]; const float* t2b = (const float*)d_in[29];
    const float* g2  = (const float*)d_in[30]; const float* be2 = (const float*)d_in[31];
    const float* pw  = (const float*)d_in[32];
    const float* l1W = (const float*)d_in[33]; const float* l1b = (const float*)d_in[34];
    const float* l2W = (const float*)d_in[35]; const float* l2b = (const float*)d_in[36];
    const float* l3W = (const float*)d_in[37]; const float* l3b = (const float*)d_in[38];

    char* ws = (char*)d_ws;
    unsigned short* C   = (unsigned short*)ws;                     // [NN,1088] bf16
    unsigned short* Hhi = (unsigned short*)(ws + (size_t)NN * NCAT * 2); // [NN,320]
    unsigned short* Hlo = Hhi + (size_t)NN * HCP;
    float* bT   = (float*)(Hlo + (size_t)NN * HCP);                // [NN,64] f32
    float* bT2  = bT + (size_t)NN * 64;                            // [NN,64] f32
    float* bcat1  = bT2 + (size_t)NN * 64;                         // [1088]
    float* bcat2  = bcat1 + NCAT;
    float* stats1 = bcat2 + NCAT;                                  // [128]
    float* stats2 = stats1 + 128;
    float* Wbf1   = stats2 + 128;                                  // [576]
    float* Wbf2   = Wbf1 + 576;
    unsigned short* WThi1  = (unsigned short*)(Wbf2 + 576);        // [1088][64]
    unsigned short* WTlo1  = WThi1 + (size_t)NCAT * 64;
    unsigned short* WThi2  = WTlo1 + (size_t)NCAT * 64;
    unsigned short* WTlo2  = WThi2 + (size_t)NCAT * 64;
    unsigned short* tWThi1 = WTlo2 + (size_t)NCAT * 64;            // [64][320]
    unsigned short* tWTlo1 = tWThi1 + 64 * HCP;
    unsigned short* tWThi2 = tWTlo1 + 64 * HCP;
    unsigned short* tWTlo2 = tWThi2 + 64 * HCP;

    const dim3 blk(256);

    prep_all<<<130, blk, 0, stream>>>(
        Wq1, bq1, Wk1, bk1, Wv1, bv1, Ws1, bs1, We1, t1W, Wb1,
        WThi1, WTlo1, bcat1, tWThi1, tWTlo1, Wbf1, stats1,
        Wq2, bq2, Wk2, bk2, Wv2, bv2, Ws2, bs2, We2, t2W, Wb2,
        WThi2, WTlo2, bcat2, tWThi2, tWTlo2, Wbf2, stats2);

    // ---- layer 1 ----
    proj_mfma<<<512, blk, 0, stream>>>(x, nullptr, nullptr, nullptr,
                                       WThi1, WTlo1, bcat1, C);
    attn_fused<<<NN / 4, blk, 0, stream>>>(C, Wbf1, srcI, ea, Hhi, Hlo);
    gemm_t<<<512, blk, 0, stream>>>(Hhi, Hlo, tWThi1, tWTlo1, t1b, bT, stats1);

    // ---- layer 2 (BN of layer 1 fused into proj staging) ----
    proj_mfma<<<512, blk, 0, stream>>>(bT, stats1, g1, be1,
                                       WThi2, WTlo2, bcat2, C);
    attn_fused<<<NN / 4, blk, 0, stream>>>(C, Wbf2, srcI, ea, Hhi, Hlo);
    gemm_t<<<512, blk, 0, stream>>>(Hhi, Hlo, tWThi2, tWTlo2, t2b, bT2, stats2);

    // ---- pooling + head (BN of layer 2 fused into load) ----
    pool_mlp<<<NG, 128, 0, stream>>>(bT2, stats2, g2, be2, pw,
                                     l1W, l1b, l2W, l2b, l3W, l3b,
                                     (float*)d_out);
}

// Round 14
// 193.322 us; speedup vs baseline: 1.1419x; 1.0445x over previous
//
#include <hip/hip_runtime.h>
#include <math.h>

#define NN 32768
#define NG 256
#define DEG 8
#define HC 256
#define NCAT 1088          // Q(256)|KV interleaved(512)|S(768..1023)|QE(1024..1087)
#define HCP 320            // H'(256) | zb(64)
#define KTOP 64
#define EPSBN 1e-5f

typedef __attribute__((ext_vector_type(8))) short short8v;   // 8 bf16
typedef __attribute__((ext_vector_type(4))) float f32x4;

// ---------------- bf16 helpers ----------------
__device__ inline float bf2f(unsigned short u) {
    union { unsigned int i; float f; } c; c.i = ((unsigned int)u) << 16; return c.f;
}
__device__ inline unsigned short f2bf(float f) {
    union { float f; unsigned int i; } c; c.f = f;
    unsigned int r = c.i + 0x7FFFu + ((c.i >> 16) & 1u);
    return (unsigned short)(r >> 16);
}
// hi = RNE bf16; lo = truncated residual
__device__ inline void split2(float v, unsigned short& hi, unsigned short& lo) {
    hi = f2bf(v);
    union { float f; unsigned int i; } c; c.f = v - bf2f(hi);
    lo = (unsigned short)(c.i >> 16);
}
// column permutation: K old 256..511 and V old 512..767 interleave per 4-group
__device__ inline int permcol(int n) {
    if (n < 256 || n >= 768) return n;
    if (n < 512) { int l = n - 256; return 256 + ((l >> 2) << 3) + (l & 3); }
    int l = n - 512; return 256 + ((l >> 2) << 3) + 4 + (l & 3);
}

// ---------------------------------------------------------------------------
// prep device body (65 logical blocks per layer)
// ---------------------------------------------------------------------------
__device__ void prep_dev(int b, int t,
    const float* __restrict__ Wq, const float* __restrict__ bq,
    const float* __restrict__ Wk, const float* __restrict__ bk,
    const float* __restrict__ Wv, const float* __restrict__ bv,
    const float* __restrict__ Ws, const float* __restrict__ bs,
    const float* __restrict__ We, const float* __restrict__ tW,
    const float* __restrict__ Wb,
    unsigned short* __restrict__ WThi, unsigned short* __restrict__ WTlo,
    float* __restrict__ bcat,
    unsigned short* __restrict__ tWThi, unsigned short* __restrict__ tWTlo,
    float* __restrict__ Wbf, float* __restrict__ stats)
{
    if (b < 16) {
        int n = b * 64 + (t >> 2);          // OLD column index
        int cc = n & 255;
        const float* src = (n < 256) ? Wq : (n < 512) ? Wk : (n < 768) ? Wv : Ws;
        int p = permcol(n);                 // NEW row position
        int k0 = (t & 3) * 16;
        #pragma unroll
        for (int k = k0; k < k0 + 16; k++) {
            unsigned short h, l;
            split2(src[k * 256 + cc], h, l);
            WThi[p * 64 + k] = h; WTlo[p * 64 + k] = l;
        }
    } else if (b < 32) {
        int idx = (b - 16) * 256 + t;
        int k = idx >> 6, o = idx & 63;
        int h = o >> 4, f = o & 15;
        const float* wq = Wq + k * 256 + h * 64;
        const float* we = We + f * 256 + h * 64;
        float s = 0.f;
        #pragma unroll
        for (int d = 0; d < 64; d++) s += wq[d] * we[d];
        unsigned short hh, ll;
        split2(s, hh, ll);
        WThi[(1024 + o) * 64 + k] = hh; WTlo[(1024 + o) * 64 + k] = ll;
    } else if (b < 48) {
        int idx = (b - 32) * 256 + t;
        int kp = idx >> 6, n = idx & 63;
        int h = kp >> 4, f = kp & 15;
        const float* we = We + f * 256 + h * 64;
        const float* tw = tW + (h * 64) * 64 + n;
        float s = 0.f;
        #pragma unroll
        for (int d = 0; d < 64; d++) s += we[d] * tw[d * 64];
        unsigned short hh, ll;
        split2(s, hh, ll);
        tWThi[n * HCP + 256 + kp] = hh; tWTlo[n * HCP + 256 + kp] = ll;
    } else if (b < 64) {
        int base = (b - 48) * 1024 + t * 4;
        #pragma unroll
        for (int i = 0; i < 4; i++) {
            int idx = base + i;
            int n = idx >> 8, k = idx & 255;
            unsigned short h, l;
            split2(tW[k * 64 + n], h, l);
            tWThi[n * HCP + k] = h; tWTlo[n * HCP + k] = l;
        }
    } else {
        if (t < 128) stats[t] = 0.f;
        Wbf[t]       = Wb[t]       + Wb[512 + t];   // w13
        Wbf[256 + t] = Wb[256 + t] - Wb[512 + t];   // w23
        for (int c = t; c < 1024; c += 256) {
            int cc = c & 255;
            float v = (c < 256) ? bq[cc] : (c < 512) ? bk[cc] : (c < 768) ? bv[cc] : bs[cc];
            bcat[permcol(c)] = v;
        }
        if (t < 64) {
            int h = t >> 4, f = t & 15;
            const float* we = We + f * 256 + h * 64;
            float s = 0.f, sb = 0.f;
            #pragma unroll
            for (int d = 0; d < 64; d++) {
                s  += we[d] * (Wb[h * 64 + d] + Wb[512 + h * 64 + d]);
                sb += we[d] * bq[h * 64 + d];
            }
            Wbf[512 + t] = s;        // we13
            bcat[1024 + t] = sb;     // qe bias
        }
    }
}

__global__ __launch_bounds__(256) void prep_all(
    const float* Wq1, const float* bq1, const float* Wk1, const float* bk1,
    const float* Wv1, const float* bv1, const float* Ws1, const float* bs1,
    const float* We1, const float* t1W, const float* Wb1,
    unsigned short* WThi1, unsigned short* WTlo1, float* bcat1,
    unsigned short* tWThi1, unsigned short* tWTlo1, float* Wbf1, float* stats1,
    const float* Wq2, const float* bq2, const float* Wk2, const float* bk2,
    const float* Wv2, const float* bv2, const float* Ws2, const float* bs2,
    const float* We2, const float* t2W, const float* Wb2,
    unsigned short* WThi2, unsigned short* WTlo2, float* bcat2,
    unsigned short* tWThi2, unsigned short* tWTlo2, float* Wbf2, float* stats2)
{
    const int b = blockIdx.x, t = threadIdx.x;
    if (b < 65)
        prep_dev(b, t, Wq1, bq1, Wk1, bk1, Wv1, bv1, Ws1, bs1, We1, t1W, Wb1,
                 WThi1, WTlo1, bcat1, tWThi1, tWTlo1, Wbf1, stats1);
    else
        prep_dev(b - 65, t, Wq2, bq2, Wk2, bk2, Wv2, bv2, Ws2, bs2, We2, t2W, Wb2,
                 WThi2, WTlo2, bcat2, tWThi2, tWTlo2, Wbf2, stats2);
}

// ---------------------------------------------------------------------------
// MFMA projection (split-bf16): C_bf16[M,1088] = A'[M,64] @ W[64,1088] + bcat
// A' = A or BN(A) applied inline while staging. Grid (17 col-tiles, 512 rows).
// ---------------------------------------------------------------------------
__global__ __launch_bounds__(256) void proj_mfma(
    const float* __restrict__ A, const float* __restrict__ stats,
    const float* __restrict__ gbn, const float* __restrict__ bbn,
    const unsigned short* __restrict__ WThi, const unsigned short* __restrict__ WTlo,
    const float* __restrict__ bcat, unsigned short* __restrict__ C)
{
    __shared__ char smem[32768];
    unsigned short* AhiL = (unsigned short*)smem;            // [64][64]
    unsigned short* AloL = AhiL + 4096;
    unsigned short* WhiL = AloL + 4096;
    unsigned short* WloL = WhiL + 4096;
    float* CL = (float*)smem;                                // [64][68] reuse
    __shared__ float scl[64], sft[64];
    const int t = threadIdx.x;
    const int n0 = blockIdx.x * 64;
    const int row0 = blockIdx.y * 64;
    const int w = t >> 6, l = t & 63;
    const int lr = l & 15, lg = l >> 4, ls = l & 7;

    if (t < 64) {
        if (stats) {
            float mean = stats[t] * (1.f / NN);
            float var  = stats[64 + t] * (1.f / NN) - mean * mean;
            float s = gbn[t] * rsqrtf(var + EPSBN);
            scl[t] = s; sft[t] = bbn[t] - mean * s;
        } else { scl[t] = 1.f; sft[t] = 0.f; }
    }
    __syncthreads();

    #pragma unroll
    for (int g = 0; g < 2; g++) {
        int idx = t * 8 + g * 2048;
        int r = idx >> 6, c = idx & 63;
        int ch = (c >> 3) ^ (r & 7);
        float4 a0 = *(const float4*)(A + (size_t)(row0 + r) * 64 + c);
        float4 a1 = *(const float4*)(A + (size_t)(row0 + r) * 64 + c + 4);
        float av[8] = {a0.x, a0.y, a0.z, a0.w, a1.x, a1.y, a1.z, a1.w};
        short8v vh, vl;
        #pragma unroll
        for (int j = 0; j < 8; j++) {
            float v = av[j] * scl[c + j] + sft[c + j];
            unsigned short h2, l2;
            split2(v, h2, l2);
            vh[j] = (short)h2; vl[j] = (short)l2;
        }
        *(short8v*)(AhiL + r * 64 + ch * 8) = vh;
        *(short8v*)(AloL + r * 64 + ch * 8) = vl;
        *(short8v*)(WhiL + r * 64 + ch * 8) =
            *(const short8v*)(WThi + (size_t)(n0 + r) * 64 + c);
        *(short8v*)(WloL + r * 64 + ch * 8) =
            *(const short8v*)(WTlo + (size_t)(n0 + r) * 64 + c);
    }
    __syncthreads();

    f32x4 acc[4] = {};
    #pragma unroll
    for (int kk = 0; kk < 2; kk++) {
        int ch = (kk * 4 + lg) ^ ls;
        short8v ah = *(short8v*)(AhiL + (w * 16 + lr) * 64 + ch * 8);
        short8v al = *(short8v*)(AloL + (w * 16 + lr) * 64 + ch * 8);
        #pragma unroll
        for (int nt = 0; nt < 4; nt++) {
            short8v bh = *(short8v*)(WhiL + (nt * 16 + lr) * 64 + ch * 8);
            short8v bl = *(short8v*)(WloL + (nt * 16 + lr) * 64 + ch * 8);
            acc[nt] = __builtin_amdgcn_mfma_f32_16x16x32_bf16(ah, bh, acc[nt], 0, 0, 0);
            acc[nt] = __builtin_amdgcn_mfma_f32_16x16x32_bf16(al, bh, acc[nt], 0, 0, 0);
            acc[nt] = __builtin_amdgcn_mfma_f32_16x16x32_bf16(ah, bl, acc[nt], 0, 0, 0);
        }
    }
    __syncthreads();
    #pragma unroll
    for (int nt = 0; nt < 4; nt++)
        #pragma unroll
        for (int r = 0; r < 4; r++)
            CL[(w * 16 + lg * 4 + r) * 68 + nt * 16 + lr] = acc[nt][r];
    __syncthreads();
    {
        int r = t >> 2, cb = (t & 3) * 16;
        #pragma unroll
        for (int jj = 0; jj < 2; jj++) {
            f32x4 p0 = *(f32x4*)(CL + r * 68 + cb + jj * 8);
            f32x4 p1 = *(f32x4*)(CL + r * 68 + cb + jj * 8 + 4);
            float4 b0 = *(const float4*)(bcat + n0 + cb + jj * 8);
            float4 b1 = *(const float4*)(bcat + n0 + cb + jj * 8 + 4);
            short8v o;
            o[0] = (short)f2bf(p0[0] + b0.x); o[1] = (short)f2bf(p0[1] + b0.y);
            o[2] = (short)f2bf(p0[2] + b0.z); o[3] = (short)f2bf(p0[3] + b0.w);
            o[4] = (short)f2bf(p1[0] + b1.x); o[5] = (short)f2bf(p1[1] + b1.y);
            o[6] = (short)f2bf(p1[2] + b1.z); o[7] = (short)f2bf(p1[3] + b1.w);
            *(short8v*)(C + (size_t)(row0 + r) * NCAT + n0 + cb + jj * 8) = o;
        }
    }
}

// ---------------------------------------------------------------------------
// MFMA transform (split-bf16): T_f32[M,64] = relu(A[M,320] @ W[320,64] + b)
// A = H' hi/lo pair. Epilogue accumulates BN stats via atomics.
// ---------------------------------------------------------------------------
__global__ __launch_bounds__(256) void gemm_t(
    const unsigned short* __restrict__ Ahi, const unsigned short* __restrict__ Alo,
    const unsigned short* __restrict__ WThi, const unsigned short* __restrict__ WTlo,
    const float* __restrict__ bias, float* __restrict__ Tout,
    float* __restrict__ stats)
{
    __shared__ char smem[32768];
    unsigned short* AhiL = (unsigned short*)smem;
    unsigned short* AloL = AhiL + 4096;
    unsigned short* WhiL = AloL + 4096;
    unsigned short* WloL = WhiL + 4096;
    float* CL = (float*)smem;
    const int t = threadIdx.x;
    const int row0 = blockIdx.x * 64;
    const int w = t >> 6, l = t & 63;
    const int lr = l & 15, lg = l >> 4, ls = l & 7;
    f32x4 acc[4] = {};
    for (int kt = 0; kt < 5; kt++) {
        if (kt) __syncthreads();
        #pragma unroll
        for (int g = 0; g < 2; g++) {
            int idx = t * 8 + g * 2048;
            int r = idx >> 6, c = idx & 63;
            int ch = (c >> 3) ^ (r & 7);
            *(short8v*)(AhiL + r * 64 + ch * 8) =
                *(const short8v*)(Ahi + (size_t)(row0 + r) * HCP + kt * 64 + c);
            *(short8v*)(AloL + r * 64 + ch * 8) =
                *(const short8v*)(Alo + (size_t)(row0 + r) * HCP + kt * 64 + c);
            *(short8v*)(WhiL + r * 64 + ch * 8) =
                *(const short8v*)(WThi + r * HCP + kt * 64 + c);
            *(short8v*)(WloL + r * 64 + ch * 8) =
                *(const short8v*)(WTlo + r * HCP + kt * 64 + c);
        }
        __syncthreads();
        #pragma unroll
        for (int kk = 0; kk < 2; kk++) {
            int ch = (kk * 4 + lg) ^ ls;
            short8v ah = *(short8v*)(AhiL + (w * 16 + lr) * 64 + ch * 8);
            short8v al = *(short8v*)(AloL + (w * 16 + lr) * 64 + ch * 8);
            #pragma unroll
            for (int nt = 0; nt < 4; nt++) {
                short8v bh = *(short8v*)(WhiL + (nt * 16 + lr) * 64 + ch * 8);
                short8v bl = *(short8v*)(WloL + (nt * 16 + lr) * 64 + ch * 8);
                acc[nt] = __builtin_amdgcn_mfma_f32_16x16x32_bf16(ah, bh, acc[nt], 0, 0, 0);
                acc[nt] = __builtin_amdgcn_mfma_f32_16x16x32_bf16(al, bh, acc[nt], 0, 0, 0);
                acc[nt] = __builtin_amdgcn_mfma_f32_16x16x32_bf16(ah, bl, acc[nt], 0, 0, 0);
            }
        }
    }
    __syncthreads();
    #pragma unroll
    for (int nt = 0; nt < 4; nt++)
        #pragma unroll
        for (int r = 0; r < 4; r++)
            CL[(w * 16 + lg * 4 + r) * 68 + nt * 16 + lr] = acc[nt][r];
    __syncthreads();
    {
        int r = t >> 2, cb = (t & 3) * 16;
        #pragma unroll
        for (int jj = 0; jj < 4; jj++) {
            f32x4 p = *(f32x4*)(CL + r * 68 + cb + jj * 4);
            float4 bb = *(const float4*)(bias + cb + jj * 4);
            float4 o;
            o.x = fmaxf(p[0] + bb.x, 0.f); o.y = fmaxf(p[1] + bb.y, 0.f);
            o.z = fmaxf(p[2] + bb.z, 0.f); o.w = fmaxf(p[3] + bb.w, 0.f);
            *(float4*)(Tout + (size_t)(row0 + r) * 64 + cb + jj * 4) = o;
        }
    }
    if (t < 64) {
        float bb = bias[t];
        float s = 0.f, s2 = 0.f;
        #pragma unroll 8
        for (int r = 0; r < 64; r++) {
            float v = fmaxf(CL[r * 68 + t] + bb, 0.f);
            s += v; s2 += v * v;
        }
        atomicAdd(&stats[t], s);
        atomicAdd(&stats[64 + t], s2);
    }
}

// ---------------------------------------------------------------------------
// Attention + beta gate. 1 node per 64-lane wave, 4 ch/lane.
// KV interleaved in C: one 16B load per edge. Output H hi/lo pair.
// ---------------------------------------------------------------------------
__global__ __launch_bounds__(256, 6) void attn_fused(
    const unsigned short* __restrict__ C,
    const float* __restrict__ Wbf,
    const int* __restrict__ srcIdx, const float* __restrict__ EA,
    unsigned short* __restrict__ Hhi, unsigned short* __restrict__ Hlo)
{
    const int t = threadIdx.x;
    const int lane = t & 63;
    const int wave = t >> 6;
    const int bid = blockIdx.x;
    const int swz = (bid & 7) * 1024 + (bid >> 3);  // 8192 blocks, XCD chunks
    const int n = swz * 4 + wave;                   // 4 nodes per block
    const int c0 = lane * 4;                        // 4 channels/lane
    const int h = lane >> 4;                        // head
    const int fi = lane & 15;                       // edge-feature index

    const unsigned short* rowN = C + (size_t)n * NCAT;
    ushort4 qv = *(const ushort4*)(rowN + c0);
    float q0 = bf2f(qv.x), q1 = bf2f(qv.y), q2 = bf2f(qv.z), q3 = bf2f(qv.w);
    float qe_l = bf2f(rowN[1024 + h * 16 + fi]);

    const int ebase = n * DEG;
    int sj = srcIdx[ebase + (lane & 7)];
    int ss[DEG];
    #pragma unroll
    for (int j = 0; j < DEG; j++) ss[j] = __shfl(sj, j);

    // batched KV + EA loads (one 16B gather per edge: K c0..c0+3 | V c0..c0+3)
    short8v kv[DEG];
    float eav[DEG];
    #pragma unroll
    for (int j = 0; j < DEG; j++) {
        kv[j] = *(const short8v*)(C + (size_t)ss[j] * NCAT + 256 + lane * 8);
        eav[j] = EA[(size_t)(ebase + j) * 16 + fi];
    }
    float alpha[DEG];
    #pragma unroll
    for (int j = 0; j < DEG; j++) {
        float d = eav[j] * qe_l
                + q0 * bf2f((unsigned short)kv[j][0]) + q1 * bf2f((unsigned short)kv[j][1])
                + q2 * bf2f((unsigned short)kv[j][2]) + q3 * bf2f((unsigned short)kv[j][3]);
        d += __shfl_xor(d, 1); d += __shfl_xor(d, 2);
        d += __shfl_xor(d, 4); d += __shfl_xor(d, 8);
        alpha[j] = d * 0.125f;                      // 1/sqrt(64)
    }
    float mx = alpha[0];
    #pragma unroll
    for (int j = 1; j < DEG; j++) mx = fmaxf(mx, alpha[j]);
    float wsum = 0.f;
    #pragma unroll
    for (int j = 0; j < DEG; j++) { alpha[j] = __expf(alpha[j] - mx); wsum += alpha[j]; }
    float inv = __builtin_amdgcn_rcpf(wsum);

    // weighted V sum from the already-loaded registers; z accumulation
    float o0 = 0.f, o1 = 0.f, o2 = 0.f, o3 = 0.f, eg = 0.f;
    #pragma unroll
    for (int j = 0; j < DEG; j++) {
        float wj = alpha[j] * inv;
        eg += wj * eav[j];
        o0 += wj * bf2f((unsigned short)kv[j][4]);
        o1 += wj * bf2f((unsigned short)kv[j][5]);
        o2 += wj * bf2f((unsigned short)kv[j][6]);
        o3 += wj * bf2f((unsigned short)kv[j][7]);
    }

    ushort4 sv = *(const ushort4*)(rowN + 768 + c0);
    float xr0 = bf2f(sv.x), xr1 = bf2f(sv.y), xr2 = bf2f(sv.z), xr3 = bf2f(sv.w);

    // beta logit: o.w13 + xr.w23 + z.we13 (we13 index == lane)
    float part = eg * Wbf[512 + lane];
    {
        f32x4 w13 = *(const f32x4*)(Wbf + c0);
        f32x4 w23 = *(const f32x4*)(Wbf + 256 + c0);
        part += o0 * w13[0] + o1 * w13[1] + o2 * w13[2] + o3 * w13[3];
        part += xr0 * w23[0] + xr1 * w23[1] + xr2 * w23[2] + xr3 * w23[3];
    }
    part += __shfl_xor(part, 1);  part += __shfl_xor(part, 2);
    part += __shfl_xor(part, 4);  part += __shfl_xor(part, 8);
    part += __shfl_xor(part, 16); part += __shfl_xor(part, 32);
    float beta = __builtin_amdgcn_rcpf(1.f + __expf(-part));
    float omb = 1.f - beta;

    ushort4 hh, hl;
    split2(beta * xr0 + omb * o0, hh.x, hl.x);
    split2(beta * xr1 + omb * o1, hh.y, hl.y);
    split2(beta * xr2 + omb * o2, hh.z, hl.z);
    split2(beta * xr3 + omb * o3, hh.w, hl.w);
    *(ushort4*)(Hhi + (size_t)n * HCP + c0) = hh;
    *(ushort4*)(Hlo + (size_t)n * HCP + c0) = hl;

    unsigned short zh, zl;
    split2(omb * eg, zh, zl);
    Hhi[(size_t)n * HCP + 256 + lane] = zh;
    Hlo[(size_t)n * HCP + 256 + lane] = zl;
}

// ---------------------------------------------------------------------------
// TopK pooling + readout + MLP head. BN applied inline from stats.
// ---------------------------------------------------------------------------
__global__ __launch_bounds__(128) void pool_mlp(
    const float* __restrict__ Hn, const float* __restrict__ stats,
    const float* __restrict__ gbn, const float* __restrict__ bbn,
    const float* __restrict__ pw,
    const float* __restrict__ W1, const float* __restrict__ b1,
    const float* __restrict__ W2, const float* __restrict__ b2,
    const float* __restrict__ W3, const float* __restrict__ b3,
    float* __restrict__ out)
{
    __shared__ float sh[128][65];
    __shared__ float spw[64];
    __shared__ float sc[128];
    __shared__ float sscale[128];
    __shared__ int   skeep[128];
    __shared__ float rmax[2][64], rsum[2][64];
    __shared__ float srep[128];
    __shared__ float sh1[256];
    __shared__ float sh2[128];
    __shared__ float wred[2];
    __shared__ float scl[64], sft[64];
    const int g = blockIdx.x, t = threadIdx.x;

    if (t < 64) {
        float mean = stats[t] * (1.f / NN);
        float var  = stats[64 + t] * (1.f / NN) - mean * mean;
        float s = gbn[t] * rsqrtf(var + EPSBN);
        scl[t] = s; sft[t] = bbn[t] - mean * s;
        spw[t] = pw[t];
    }
    __syncthreads();
    for (int i = t; i < 128 * 64; i += 128) {
        int c = i & 63;
        sh[i >> 6][c] = Hn[(size_t)g * 128 * 64 + i] * scl[c] + sft[c];
    }
    __syncthreads();

    float nw = 0.f;
    #pragma unroll
    for (int i = 0; i < 64; i++) { float w = spw[i]; nw += w * w; }
    float invn = rsqrtf(nw);

    float s = 0.f;
    #pragma unroll
    for (int i = 0; i < 64; i++) s += sh[t][i] * spw[i];
    s *= invn;
    sc[t] = s;
    __syncthreads();

    int rank = 0;
    for (int m = 0; m < 128; m++) {
        float sm = sc[m];
        rank += (sm > s) || (sm == s && m < t);
    }
    skeep[t] = (rank < KTOP);
    sscale[t] = tanhf(s);
    __syncthreads();

    {
        int c = t & 63, half = t >> 6;
        float mxv = -1e30f, sm = 0.f;
        for (int r = half * 64; r < half * 64 + 64; r++) {
            if (skeep[r]) {
                float v = sh[r][c] * sscale[r];
                mxv = fmaxf(mxv, v); sm += v;
            }
        }
        rmax[half][c] = mxv; rsum[half][c] = sm;
    }
    __syncthreads();
    if (t < 64) {
        srep[t] = fmaxf(rmax[0][t], rmax[1][t]);
        srep[64 + t] = (rsum[0][t] + rsum[1][t]) * (1.f / KTOP);
    }
    __syncthreads();

    #pragma unroll
    for (int jj = 0; jj < 2; jj++) {
        int j = t + jj * 128;
        float a = b1[j];
        for (int c2 = 0; c2 < 128; c2++) a += srep[c2] * W1[c2 * 256 + j];
        sh1[j] = fmaxf(a, 0.f);
    }
    __syncthreads();
    {
        float a = b2[t];
        for (int c2 = 0; c2 < 256; c2++) a += sh1[c2] * W2[c2 * 128 + t];
        sh2[t] = fmaxf(a, 0.f);
    }
    __syncthreads();
    float p = sh2[t] * W3[t];
    p += __shfl_xor(p, 1);  p += __shfl_xor(p, 2);  p += __shfl_xor(p, 4);
    p += __shfl_xor(p, 8);  p += __shfl_xor(p, 16); p += __shfl_xor(p, 32);
    if ((t & 63) == 0) wred[t >> 6] = p;
    __syncthreads();
    if (t == 0) out[g] = wred[0] + wred[1] + b3[0];
}

// ---------------------------------------------------------------------------
extern "C" void kernel_launch(void* const* d_in, const int* in_sizes, int n_in,
                              void* d_out, int out_size, void* d_ws, size_t ws_size,
                              hipStream_t stream)
{
    const float* x    = (const float*)d_in[0];
    const int*   ei   = (const int*)  d_in[1];
    const float* ea   = (const float*)d_in[2];
    const int*   srcI = ei;
    const float* Wq1 = (const float*)d_in[4];  const float* bq1 = (const float*)d_in[5];
    const float* Wk1 = (const float*)d_in[6];  const float* bk1 = (const float*)d_in[7];
    const float* Wv1 = (const float*)d_in[8];  const float* bv1 = (const float*)d_in[9];
    const float* We1 = (const float*)d_in[10];
    const float* Ws1 = (const float*)d_in[11]; const float* bs1 = (const float*)d_in[12];
    const float* Wb1 = (const float*)d_in[13];
    const float* t1W = (const float*)d_in[14]; const float* t1b = (const float*)d_in[15];
    const float* g1  = (const float*)d_in[16]; const float* be1 = (const float*)d_in[17];
    const float* Wq2 = (const float*)d_in[18]; const float* bq2 = (const float*)d_in[19];
    const float* Wk2 = (const float*)d_in[20]; const float* bk2 = (const float*)d_in[21];
    const float* Wv2 = (const float*)d_in[22]; const float* bv2 = (const float*)d_in[23];
    const float* We2 = (const float*)d_in[24];
    const float* Ws2 = (const float*)d_in[25]; const float* bs2 = (const float*)d_in[26];
    const float* Wb2 = (const float*)d_in[27];
    const float* t2W = (const float*)d_in[28]; const float* t2b = (const float*)d_in[29];
    const float* g2  = (const float*)d_in[30]; const float* be2 = (const float*)d_in[31];
    const float* pw  = (const float*)d_in[32];
    const float* l1W = (const float*)d_in[33]; const float* l1b = (const float*)d_in[34];
    const float* l2W = (const float*)d_in[35]; const float* l2b = (const float*)d_in[36];
    const float* l3W = (const float*)d_in[37]; const float* l3b = (const float*)d_in[38];

    char* ws = (char*)d_ws;
    unsigned short* C   = (unsigned short*)ws;                     // [NN,1088] bf16
    unsigned short* Hhi = (unsigned short*)(ws + (size_t)NN * NCAT * 2); // [NN,320]
    unsigned short* Hlo = Hhi + (size_t)NN * HCP;
    float* bT   = (float*)(Hlo + (size_t)NN * HCP);                // [NN,64] f32
    float* bT2  = bT + (size_t)NN * 64;                            // [NN,64] f32
    float* bcat1  = bT2 + (size_t)NN * 64;                         // [1088]
    float* bcat2  = bcat1 + NCAT;
    float* stats1 = bcat2 + NCAT;                                  // [128]
    float* stats2 = stats1 + 128;
    float* Wbf1   = stats2 + 128;                                  // [576]
    float* Wbf2   = Wbf1 + 576;
    unsigned short* WThi1  = (unsigned short*)(Wbf2 + 576);        // [1088][64]
    unsigned short* WTlo1  = WThi1 + (size_t)NCAT * 64;
    unsigned short* WThi2  = WTlo1 + (size_t)NCAT * 64;
    unsigned short* WTlo2  = WThi2 + (size_t)NCAT * 64;
    unsigned short* tWThi1 = WTlo2 + (size_t)NCAT * 64;            // [64][320]
    unsigned short* tWTlo1 = tWThi1 + 64 * HCP;
    unsigned short* tWThi2 = tWTlo1 + 64 * HCP;
    unsigned short* tWTlo2 = tWThi2 + 64 * HCP;

    const dim3 blk(256);
    const dim3 gProj(17, 512);

    prep_all<<<130, blk, 0, stream>>>(
        Wq1, bq1, Wk1, bk1, Wv1, bv1, Ws1, bs1, We1, t1W, Wb1,
        WThi1, WTlo1, bcat1, tWThi1, tWTlo1, Wbf1, stats1,
        Wq2, bq2, Wk2, bk2, Wv2, bv2, Ws2, bs2, We2, t2W, Wb2,
        WThi2, WTlo2, bcat2, tWThi2, tWTlo2, Wbf2, stats2);

    // ---- layer 1 ----
    proj_mfma<<<gProj, blk, 0, stream>>>(x, nullptr, nullptr, nullptr,
                                         WThi1, WTlo1, bcat1, C);
    attn_fused<<<NN / 4, blk, 0, stream>>>(C, Wbf1, srcI, ea, Hhi, Hlo);
    gemm_t<<<512, blk, 0, stream>>>(Hhi, Hlo, tWThi1, tWTlo1, t1b, bT, stats1);

    // ---- layer 2 (BN of layer 1 fused into proj staging) ----
    proj_mfma<<<gProj, blk, 0, stream>>>(bT, stats1, g1, be1,
                                         WThi2, WTlo2, bcat2, C);
    attn_fused<<<NN / 4, blk, 0, stream>>>(C, Wbf2, srcI, ea, Hhi, Hlo);
    gemm_t<<<512, blk, 0, stream>>>(Hhi, Hlo, tWThi2, tWTlo2, t2b, bT2, stats2);

    // ---- pooling + head (BN of layer 2 fused into load) ----
    pool_mlp<<<NG, 128, 0, stream>>>(bT2, stats2, g2, be2, pw,
                                     l1W, l1b, l2W, l2b, l3W, l3b,
                                     (float*)d_out);
}